// Round 1
// baseline (254.740 us; speedup 1.0000x reference)
//
#include <hip/hip_runtime.h>
#include <math.h>

#define BB 64
#define LL 1024
#define HH 256
#define TT 128
#define D_ID 128
#define D_SZ 64
#define D_POS 128
#define DX 192   // D_ID + D_SZ

// ---------------------------------------------------------------- LSTM cell
__global__ void lstm_kernel(const int* __restrict__ obj_id,
                            const int* __restrict__ obj_size,
                            const float* __restrict__ c0,
                            const float* __restrict__ h0,
                            const float* __restrict__ obj_id_table,
                            const float* __restrict__ obj_size_table,
                            const float* __restrict__ W_ih,
                            const float* __restrict__ W_hh,
                            const float* __restrict__ b_ih,
                            const float* __restrict__ b_hh,
                            float* __restrict__ h_new) {
    int b = blockIdx.x;
    int j = threadIdx.x;   // 0..255 -> hidden unit
    __shared__ float xS[DX];
    __shared__ float hS[HH];
    int oid = obj_id[b], osz = obj_size[b];
    if (j < D_ID) xS[j] = obj_id_table[(size_t)oid * D_ID + j];
    else if (j < DX) xS[j] = obj_size_table[(size_t)osz * D_SZ + (j - D_ID)];
    hS[j] = h0[b * HH + j];
    __syncthreads();

    float g4[4];
#pragma unroll
    for (int g = 0; g < 4; ++g) {
        int r = g * HH + j;
        float acc = b_ih[r] + b_hh[r];
        const float4* wi = (const float4*)(W_ih + (size_t)r * DX);
#pragma unroll 4
        for (int k = 0; k < DX / 4; ++k) {
            float4 w = wi[k];
            float4 xv = *(const float4*)(xS + 4 * k);
            acc += w.x * xv.x + w.y * xv.y + w.z * xv.z + w.w * xv.w;
        }
        const float4* wh = (const float4*)(W_hh + (size_t)r * HH);
#pragma unroll 4
        for (int k = 0; k < HH / 4; ++k) {
            float4 w = wh[k];
            float4 hv = *(const float4*)(hS + 4 * k);
            acc += w.x * hv.x + w.y * hv.y + w.z * hv.z + w.w * hv.w;
        }
        g4[g] = acc;
    }
    float ig = 1.f / (1.f + expf(-g4[0]));
    float fg = 1.f / (1.f + expf(-g4[1]));
    float gg = tanhf(g4[2]);
    float og = 1.f / (1.f + expf(-g4[3]));
    float c = fg * c0[b * HH + j] + ig * gg;
    h_new[b * HH + j] = og * tanhf(c);
}

// ------------------------------------------- HP = hist @ attn_W^T, sv, rv
// grid: B*4 (32-t tiles), block 256
__global__ void proj_kernel(const float* __restrict__ history,
                            const float* __restrict__ h_new,
                            const float* __restrict__ attn_W,
                            const float* __restrict__ pos_table,
                            const float* __restrict__ scorer_W,
                            const float* __restrict__ reuse_W,
                            float* __restrict__ hp,
                            float* __restrict__ sv,
                            float* __restrict__ rv) {
    int b  = blockIdx.x >> 2;
    int t0 = (blockIdx.x & 3) * 32;
    int tid = threadIdx.x;
    int tx = tid & 15;   // d-group: d = tx + 16*i
    int ty = tid >> 4;   // t-group: t = ty + 16*j
    __shared__ float histS[32 * 68];
    __shared__ float wS[128 * 68];
    float acc[2][8];
#pragma unroll
    for (int j = 0; j < 2; ++j)
#pragma unroll
        for (int i = 0; i < 8; ++i) acc[j][i] = 0.f;
    float sva = 0.f, rva = 0.f;

    for (int kc = 0; kc < 4; ++kc) {
        int h0c = kc * 64;
#pragma unroll
        for (int i = 0; i < 2; ++i) {        // 32x64 hist chunk
            int idx = i * 256 + tid;
            int t = idx >> 4;
            int hq = (idx & 15) * 4;
            int gt = t0 + t;
            const float* src = (gt < TT - 1)
                ? (history + ((size_t)b * (TT - 1) + gt) * HH + h0c + hq)
                : (h_new + (size_t)b * HH + h0c + hq);
            *(float4*)(histS + t * 68 + hq) = *(const float4*)src;
        }
#pragma unroll
        for (int i = 0; i < 8; ++i) {        // 128x64 attn_W chunk
            int idx = i * 256 + tid;
            int d = idx >> 4;
            int hq = (idx & 15) * 4;
            *(float4*)(wS + d * 68 + hq) =
                *(const float4*)(attn_W + (size_t)d * HH + h0c + hq);
        }
        __syncthreads();

        for (int h = 0; h < 64; h += 4) {
            float4 hv[2];
#pragma unroll
            for (int j = 0; j < 2; ++j)
                hv[j] = *(const float4*)(histS + (ty + 16 * j) * 68 + h);
#pragma unroll
            for (int i = 0; i < 8; ++i) {
                float4 wv = *(const float4*)(wS + (tx + 16 * i) * 68 + h);
#pragma unroll
                for (int j = 0; j < 2; ++j)
                    acc[j][i] += hv[j].x * wv.x + hv[j].y * wv.y +
                                 hv[j].z * wv.z + hv[j].w * wv.w;
            }
        }
        if (tid < 32) {   // sv/rv hist part for t = t0+tid
            float s = 0.f, r = 0.f;
            for (int h = 0; h < 64; ++h) {
                float hval = histS[tid * 68 + h];
                s += hval * scorer_W[h0c + h];
                r += hval * reuse_W[h0c + h];
            }
            sva += s; rva += r;
        }
        __syncthreads();
    }
#pragma unroll
    for (int j = 0; j < 2; ++j) {
        int t = t0 + ty + 16 * j;
#pragma unroll
        for (int i = 0; i < 8; ++i) {
            int d = tx + 16 * i;
            hp[((size_t)b * TT + t) * D_ID + d] = acc[j][i];
        }
    }
    if (tid < 32) {
        int t = t0 + tid;
        float s = sva, r = rva;
        for (int p = 0; p < D_POS; ++p) {
            float pv = pos_table[(size_t)t * D_POS + p];
            s += pv * scorer_W[HH + p];
            r += pv * reuse_W[HH + p];
        }
        sv[b * TT + t] = s;
        rv[b * TT + t] = r;
    }
}

// ---------------- scores = Q@HP^T, softmax over t, weighted sums -> heads
// grid: B*16 (64-l tiles), block 256
__global__ void attn_kernel(const int* __restrict__ cache_lines,
                            const float* __restrict__ obj_id_table,
                            const float* __restrict__ hp,
                            const float* __restrict__ sv,
                            const float* __restrict__ rv,
                            const float* __restrict__ scorer_b,
                            const float* __restrict__ reuse_b,
                            float* __restrict__ logits,
                            float* __restrict__ out_reuse) {
    int b  = blockIdx.x >> 4;
    int l0 = (blockIdx.x & 15) * 64;
    int tid = threadIdx.x;
    int tx = tid & 15;   // t-group: t = tx + 16*i (i<8)
    int ty = tid >> 4;   // l-group: l = ty + 16*j (j<4)
    __shared__ float qS[64 * 68];
    __shared__ float hpS[128 * 68];
    __shared__ float svS[TT];
    __shared__ float rvS[TT];
    if (tid < TT) { svS[tid] = sv[b * TT + tid]; rvS[tid] = rv[b * TT + tid]; }

    float acc[4][8];
#pragma unroll
    for (int j = 0; j < 4; ++j)
#pragma unroll
        for (int i = 0; i < 8; ++i) acc[j][i] = 0.f;

    for (int kc = 0; kc < 2; ++kc) {
        int d0 = kc * 64;
#pragma unroll
        for (int i = 0; i < 4; ++i) {        // 64x64 q chunk (gather)
            int idx = i * 256 + tid;
            int l = idx >> 4;
            int dq = (idx & 15) * 4;
            int cl = cache_lines[b * LL + l0 + l];
            *(float4*)(qS + l * 68 + dq) =
                *(const float4*)(obj_id_table + (size_t)cl * D_ID + d0 + dq);
        }
#pragma unroll
        for (int i = 0; i < 8; ++i) {        // 128x64 hp chunk
            int idx = i * 256 + tid;
            int t = idx >> 4;
            int dq = (idx & 15) * 4;
            *(float4*)(hpS + t * 68 + dq) =
                *(const float4*)(hp + ((size_t)b * TT + t) * D_ID + d0 + dq);
        }
        __syncthreads();

        for (int d = 0; d < 64; d += 4) {
            float4 qv[4];
#pragma unroll
            for (int j = 0; j < 4; ++j)
                qv[j] = *(const float4*)(qS + (ty + 16 * j) * 68 + d);
#pragma unroll
            for (int i = 0; i < 8; ++i) {
                float4 hv = *(const float4*)(hpS + (tx + 16 * i) * 68 + d);
#pragma unroll
                for (int j = 0; j < 4; ++j)
                    acc[j][i] += qv[j].x * hv.x + qv[j].y * hv.y +
                                 qv[j].z * hv.z + qv[j].w * hv.w;
            }
        }
        __syncthreads();
    }

    float sb = scorer_b[0], rb = reuse_b[0];
#pragma unroll
    for (int j = 0; j < 4; ++j) {
        float m = -1e30f;
#pragma unroll
        for (int i = 0; i < 8; ++i) m = fmaxf(m, acc[j][i]);
#pragma unroll
        for (int off = 1; off < 16; off <<= 1) m = fmaxf(m, __shfl_xor(m, off));
        float s = 0.f, lg = 0.f, rg = 0.f;
#pragma unroll
        for (int i = 0; i < 8; ++i) {
            float e = __expf(acc[j][i] - m);
            s += e;
            lg += e * svS[tx + 16 * i];
            rg += e * rvS[tx + 16 * i];
        }
#pragma unroll
        for (int off = 1; off < 16; off <<= 1) {
            s  += __shfl_xor(s, off);
            lg += __shfl_xor(lg, off);
            rg += __shfl_xor(rg, off);
        }
        if (tx == 0) {
            int l = l0 + ty + 16 * j;
            logits[b * LL + l] = lg / s + sb;
            out_reuse[(size_t)b * LL + l] = rg / s + rb;
        }
    }
}

// -------------------------------------- masked softmax over L per batch
__global__ void finalsm_kernel(const float* __restrict__ logits,
                               const int* __restrict__ lengths,
                               float* __restrict__ out_probs) {
    int b = blockIdx.x;
    int tid = threadIdx.x;
    int valid = max(lengths[b], 1);
    float v[4];
    float m = -1e30f;
#pragma unroll
    for (int i = 0; i < 4; ++i) {
        int l = tid + 256 * i;
        v[i] = (l < valid) ? logits[b * LL + l] : -1e30f;
        m = fmaxf(m, v[i]);
    }
#pragma unroll
    for (int off = 1; off < 64; off <<= 1) m = fmaxf(m, __shfl_xor(m, off));
    __shared__ float redm[4];
    __shared__ float reds[4];
    int wave = tid >> 6;
    if ((tid & 63) == 0) redm[wave] = m;
    __syncthreads();
    m = fmaxf(fmaxf(redm[0], redm[1]), fmaxf(redm[2], redm[3]));
    float e[4];
    float s = 0.f;
#pragma unroll
    for (int i = 0; i < 4; ++i) {
        int l = tid + 256 * i;
        e[i] = (l < valid) ? expf(v[i] - m) : 0.f;
        s += e[i];
    }
#pragma unroll
    for (int off = 1; off < 64; off <<= 1) s += __shfl_xor(s, off);
    if ((tid & 63) == 0) reds[wave] = s;
    __syncthreads();
    s = reds[0] + reds[1] + reds[2] + reds[3];
    float inv = 1.f / s;
#pragma unroll
    for (int i = 0; i < 4; ++i)
        out_probs[b * LL + tid + 256 * i] = e[i] * inv;
}

extern "C" void kernel_launch(void* const* d_in, const int* in_sizes, int n_in,
                              void* d_out, int out_size, void* d_ws, size_t ws_size,
                              hipStream_t stream) {
    const int*   obj_id         = (const int*)d_in[0];
    const int*   obj_size       = (const int*)d_in[1];
    const int*   cache_lines    = (const int*)d_in[2];
    const int*   lengths        = (const int*)d_in[3];
    const float* c0             = (const float*)d_in[4];
    const float* h0             = (const float*)d_in[5];
    const float* history        = (const float*)d_in[6];
    const float* obj_id_table   = (const float*)d_in[7];
    const float* obj_size_table = (const float*)d_in[8];
    const float* pos_table      = (const float*)d_in[9];
    const float* W_ih           = (const float*)d_in[10];
    const float* W_hh           = (const float*)d_in[11];
    const float* b_ih           = (const float*)d_in[12];
    const float* b_hh           = (const float*)d_in[13];
    const float* attn_W         = (const float*)d_in[14];
    const float* scorer_W       = (const float*)d_in[15];
    const float* scorer_b       = (const float*)d_in[16];
    const float* reuse_W        = (const float*)d_in[17];
    const float* reuse_b        = (const float*)d_in[18];

    float* out = (float*)d_out;
    float* out_probs = out;                 // (B, L)
    float* out_reuse = out + BB * LL;       // (B, L)

    char* ws = (char*)d_ws;
    float* h_new  = (float*)(ws);                         // B*H
    float* hp     = (float*)(ws + 65536);                 // B*T*D_ID = 4 MB
    float* sv     = (float*)(ws + 65536 + 4194304);       // B*T
    float* rv     = (float*)(ws + 65536 + 4194304 + 32768);
    float* logits = (float*)(ws + 65536 + 4194304 + 65536); // B*L

    hipLaunchKernelGGL(lstm_kernel, dim3(BB), dim3(256), 0, stream,
                       obj_id, obj_size, c0, h0, obj_id_table, obj_size_table,
                       W_ih, W_hh, b_ih, b_hh, h_new);
    hipLaunchKernelGGL(proj_kernel, dim3(BB * 4), dim3(256), 0, stream,
                       history, h_new, attn_W, pos_table, scorer_W, reuse_W,
                       hp, sv, rv);
    hipLaunchKernelGGL(attn_kernel, dim3(BB * 16), dim3(256), 0, stream,
                       cache_lines, obj_id_table, hp, sv, rv,
                       scorer_b, reuse_b, logits, out_reuse);
    hipLaunchKernelGGL(finalsm_kernel, dim3(BB), dim3(256), 0, stream,
                       logits, lengths, out_probs);
}

// Round 2
// 226.181 us; speedup vs baseline: 1.1263x; 1.1263x over previous
//
#include <hip/hip_runtime.h>
#include <math.h>

#define BB 64
#define LL 1024
#define HH 256
#define TT 128
#define D_ID 128
#define D_SZ 64
#define D_POS 128
#define DX 192   // D_ID + D_SZ

// ------------------------------------------- xh_t[448][64] = concat(x, h0)^T
// grid: 112 blocks x 256 (4 k-rows x 64 b per block), coalesced writes
__global__ void embed_kernel(const int* __restrict__ obj_id,
                             const int* __restrict__ obj_size,
                             const float* __restrict__ h0,
                             const float* __restrict__ obj_id_table,
                             const float* __restrict__ obj_size_table,
                             float* __restrict__ xh_t) {
    int tid = threadIdx.x;
    int b = tid & 63;
    int k = blockIdx.x * 4 + (tid >> 6);
    float v;
    if (k < D_ID)      v = obj_id_table[(size_t)obj_id[b] * D_ID + k];
    else if (k < DX)   v = obj_size_table[(size_t)obj_size[b] * D_SZ + (k - D_ID)];
    else               v = h0[b * HH + (k - DX)];
    xh_t[k * 64 + b] = v;
}

// --------------- gates = xh @ [W_ih|W_hh]^T + b, fused LSTM activation
// grid: 64 blocks x 256. Block bid owns hidden units j = bid*4 .. bid*4+3,
// all 4 gates (16 W rows). thread = (joff = tid>>6, b = tid&63).
// W rows are wave-uniform -> scalar (SMEM) loads; xh_t staged in LDS.
__global__ void gates_kernel(const float* __restrict__ xh_t,
                             const float* __restrict__ W_ih,
                             const float* __restrict__ W_hh,
                             const float* __restrict__ b_ih,
                             const float* __restrict__ b_hh,
                             const float* __restrict__ c0,
                             float* __restrict__ h_new) {
    int bid = blockIdx.x;
    int tid = threadIdx.x;
    int b = tid & 63;
    int joff = __builtin_amdgcn_readfirstlane(tid >> 6);
    int j = bid * 4 + joff;
    __shared__ float xhS[64 * 64];

    float acc[4];
#pragma unroll
    for (int q = 0; q < 4; ++q) acc[q] = b_ih[q * HH + j] + b_hh[q * HH + j];

    for (int kc = 0; kc < 7; ++kc) {
        // stage 64 k-rows x 64 b = 16 KB, coalesced float4
#pragma unroll
        for (int i = 0; i < 4; ++i)
            ((float4*)xhS)[i * 256 + tid] =
                ((const float4*)(xh_t + kc * 4096))[i * 256 + tid];
        __syncthreads();

        const float* w[4];
#pragma unroll
        for (int q = 0; q < 4; ++q) {
            int r = q * HH + j;
            w[q] = (kc < 3) ? (W_ih + (size_t)r * DX + kc * 64)
                            : (W_hh + (size_t)r * HH + (kc - 3) * 64);
        }
#pragma unroll 16
        for (int k = 0; k < 64; ++k) {
            float xv = xhS[k * 64 + b];
            acc[0] += w[0][k] * xv;
            acc[1] += w[1][k] * xv;
            acc[2] += w[2][k] * xv;
            acc[3] += w[3][k] * xv;
        }
        __syncthreads();
    }

    float ig = 1.f / (1.f + expf(-acc[0]));
    float fg = 1.f / (1.f + expf(-acc[1]));
    float gg = tanhf(acc[2]);
    float og = 1.f / (1.f + expf(-acc[3]));
    float c = fg * c0[b * HH + j] + ig * gg;
    h_new[b * HH + j] = og * tanhf(c);
}

// ------------------------------------------- HP = hist @ attn_W^T, sv, rv
// grid: B*4 (32-t tiles), block 256
__global__ void proj_kernel(const float* __restrict__ history,
                            const float* __restrict__ h_new,
                            const float* __restrict__ attn_W,
                            const float* __restrict__ pos_table,
                            const float* __restrict__ scorer_W,
                            const float* __restrict__ reuse_W,
                            float* __restrict__ hp,
                            float* __restrict__ sv,
                            float* __restrict__ rv) {
    int b  = blockIdx.x >> 2;
    int t0 = (blockIdx.x & 3) * 32;
    int tid = threadIdx.x;
    int tx = tid & 15;   // d-group: d = tx + 16*i
    int ty = tid >> 4;   // t-group: t = ty + 16*j
    __shared__ float histS[32 * 68];
    __shared__ float wS[128 * 68];
    float acc[2][8];
#pragma unroll
    for (int j = 0; j < 2; ++j)
#pragma unroll
        for (int i = 0; i < 8; ++i) acc[j][i] = 0.f;
    float sva = 0.f, rva = 0.f;

    for (int kc = 0; kc < 4; ++kc) {
        int h0c = kc * 64;
#pragma unroll
        for (int i = 0; i < 2; ++i) {        // 32x64 hist chunk
            int idx = i * 256 + tid;
            int t = idx >> 4;
            int hq = (idx & 15) * 4;
            int gt = t0 + t;
            const float* src = (gt < TT - 1)
                ? (history + ((size_t)b * (TT - 1) + gt) * HH + h0c + hq)
                : (h_new + (size_t)b * HH + h0c + hq);
            *(float4*)(histS + t * 68 + hq) = *(const float4*)src;
        }
#pragma unroll
        for (int i = 0; i < 8; ++i) {        // 128x64 attn_W chunk
            int idx = i * 256 + tid;
            int d = idx >> 4;
            int hq = (idx & 15) * 4;
            *(float4*)(wS + d * 68 + hq) =
                *(const float4*)(attn_W + (size_t)d * HH + h0c + hq);
        }
        __syncthreads();

        for (int h = 0; h < 64; h += 4) {
            float4 hv[2];
#pragma unroll
            for (int j = 0; j < 2; ++j)
                hv[j] = *(const float4*)(histS + (ty + 16 * j) * 68 + h);
#pragma unroll
            for (int i = 0; i < 8; ++i) {
                float4 wv = *(const float4*)(wS + (tx + 16 * i) * 68 + h);
#pragma unroll
                for (int j = 0; j < 2; ++j)
                    acc[j][i] += hv[j].x * wv.x + hv[j].y * wv.y +
                                 hv[j].z * wv.z + hv[j].w * wv.w;
            }
        }
        if (tid < 32) {   // sv/rv hist part for t = t0+tid
            float s = 0.f, r = 0.f;
            for (int h = 0; h < 64; ++h) {
                float hval = histS[tid * 68 + h];
                s += hval * scorer_W[h0c + h];
                r += hval * reuse_W[h0c + h];
            }
            sva += s; rva += r;
        }
        __syncthreads();
    }
#pragma unroll
    for (int j = 0; j < 2; ++j) {
        int t = t0 + ty + 16 * j;
#pragma unroll
        for (int i = 0; i < 8; ++i) {
            int d = tx + 16 * i;
            hp[((size_t)b * TT + t) * D_ID + d] = acc[j][i];
        }
    }
    if (tid < 32) {
        int t = t0 + tid;
        float s = sva, r = rva;
        for (int p = 0; p < D_POS; ++p) {
            float pv = pos_table[(size_t)t * D_POS + p];
            s += pv * scorer_W[HH + p];
            r += pv * reuse_W[HH + p];
        }
        sv[b * TT + t] = s;
        rv[b * TT + t] = r;
    }
}

// ---------------- scores = Q@HP^T, softmax over t, weighted sums -> heads
// grid: B*16 (64-l tiles), block 256
__global__ void attn_kernel(const int* __restrict__ cache_lines,
                            const float* __restrict__ obj_id_table,
                            const float* __restrict__ hp,
                            const float* __restrict__ sv,
                            const float* __restrict__ rv,
                            const float* __restrict__ scorer_b,
                            const float* __restrict__ reuse_b,
                            float* __restrict__ logits,
                            float* __restrict__ out_reuse) {
    int b  = blockIdx.x >> 4;
    int l0 = (blockIdx.x & 15) * 64;
    int tid = threadIdx.x;
    int tx = tid & 15;   // t-group: t = tx + 16*i (i<8)
    int ty = tid >> 4;   // l-group: l = ty + 16*j (j<4)
    __shared__ float qS[64 * 68];
    __shared__ float hpS[128 * 68];
    __shared__ float svS[TT];
    __shared__ float rvS[TT];
    if (tid < TT) { svS[tid] = sv[b * TT + tid]; rvS[tid] = rv[b * TT + tid]; }

    float acc[4][8];
#pragma unroll
    for (int j = 0; j < 4; ++j)
#pragma unroll
        for (int i = 0; i < 8; ++i) acc[j][i] = 0.f;

    for (int kc = 0; kc < 2; ++kc) {
        int d0 = kc * 64;
#pragma unroll
        for (int i = 0; i < 4; ++i) {        // 64x64 q chunk (gather)
            int idx = i * 256 + tid;
            int l = idx >> 4;
            int dq = (idx & 15) * 4;
            int cl = cache_lines[b * LL + l0 + l];
            *(float4*)(qS + l * 68 + dq) =
                *(const float4*)(obj_id_table + (size_t)cl * D_ID + d0 + dq);
        }
#pragma unroll
        for (int i = 0; i < 8; ++i) {        // 128x64 hp chunk
            int idx = i * 256 + tid;
            int t = idx >> 4;
            int dq = (idx & 15) * 4;
            *(float4*)(hpS + t * 68 + dq) =
                *(const float4*)(hp + ((size_t)b * TT + t) * D_ID + d0 + dq);
        }
        __syncthreads();

        for (int d = 0; d < 64; d += 4) {
            float4 qv[4];
#pragma unroll
            for (int j = 0; j < 4; ++j)
                qv[j] = *(const float4*)(qS + (ty + 16 * j) * 68 + d);
#pragma unroll
            for (int i = 0; i < 8; ++i) {
                float4 hv = *(const float4*)(hpS + (tx + 16 * i) * 68 + d);
#pragma unroll
                for (int j = 0; j < 4; ++j)
                    acc[j][i] += qv[j].x * hv.x + qv[j].y * hv.y +
                                 qv[j].z * hv.z + qv[j].w * hv.w;
            }
        }
        __syncthreads();
    }

    float sb = scorer_b[0], rb = reuse_b[0];
#pragma unroll
    for (int j = 0; j < 4; ++j) {
        float m = -1e30f;
#pragma unroll
        for (int i = 0; i < 8; ++i) m = fmaxf(m, acc[j][i]);
#pragma unroll
        for (int off = 1; off < 16; off <<= 1) m = fmaxf(m, __shfl_xor(m, off));
        float s = 0.f, lg = 0.f, rg = 0.f;
#pragma unroll
        for (int i = 0; i < 8; ++i) {
            float e = __expf(acc[j][i] - m);
            s += e;
            lg += e * svS[tx + 16 * i];
            rg += e * rvS[tx + 16 * i];
        }
#pragma unroll
        for (int off = 1; off < 16; off <<= 1) {
            s  += __shfl_xor(s, off);
            lg += __shfl_xor(lg, off);
            rg += __shfl_xor(rg, off);
        }
        if (tx == 0) {
            int l = l0 + ty + 16 * j;
            logits[b * LL + l] = lg / s + sb;
            out_reuse[(size_t)b * LL + l] = rg / s + rb;
        }
    }
}

// -------------------------------------- masked softmax over L per batch
__global__ void finalsm_kernel(const float* __restrict__ logits,
                               const int* __restrict__ lengths,
                               float* __restrict__ out_probs) {
    int b = blockIdx.x;
    int tid = threadIdx.x;
    int valid = max(lengths[b], 1);
    float v[4];
    float m = -1e30f;
#pragma unroll
    for (int i = 0; i < 4; ++i) {
        int l = tid + 256 * i;
        v[i] = (l < valid) ? logits[b * LL + l] : -1e30f;
        m = fmaxf(m, v[i]);
    }
#pragma unroll
    for (int off = 1; off < 64; off <<= 1) m = fmaxf(m, __shfl_xor(m, off));
    __shared__ float redm[4];
    __shared__ float reds[4];
    int wave = tid >> 6;
    if ((tid & 63) == 0) redm[wave] = m;
    __syncthreads();
    m = fmaxf(fmaxf(redm[0], redm[1]), fmaxf(redm[2], redm[3]));
    float e[4];
    float s = 0.f;
#pragma unroll
    for (int i = 0; i < 4; ++i) {
        int l = tid + 256 * i;
        e[i] = (l < valid) ? expf(v[i] - m) : 0.f;
        s += e[i];
    }
#pragma unroll
    for (int off = 1; off < 64; off <<= 1) s += __shfl_xor(s, off);
    if ((tid & 63) == 0) reds[wave] = s;
    __syncthreads();
    s = reds[0] + reds[1] + reds[2] + reds[3];
    float inv = 1.f / s;
#pragma unroll
    for (int i = 0; i < 4; ++i)
        out_probs[b * LL + tid + 256 * i] = e[i] * inv;
}

extern "C" void kernel_launch(void* const* d_in, const int* in_sizes, int n_in,
                              void* d_out, int out_size, void* d_ws, size_t ws_size,
                              hipStream_t stream) {
    const int*   obj_id         = (const int*)d_in[0];
    const int*   obj_size       = (const int*)d_in[1];
    const int*   cache_lines    = (const int*)d_in[2];
    const int*   lengths        = (const int*)d_in[3];
    const float* c0             = (const float*)d_in[4];
    const float* h0             = (const float*)d_in[5];
    const float* history        = (const float*)d_in[6];
    const float* obj_id_table   = (const float*)d_in[7];
    const float* obj_size_table = (const float*)d_in[8];
    const float* pos_table      = (const float*)d_in[9];
    const float* W_ih           = (const float*)d_in[10];
    const float* W_hh           = (const float*)d_in[11];
    const float* b_ih           = (const float*)d_in[12];
    const float* b_hh           = (const float*)d_in[13];
    const float* attn_W         = (const float*)d_in[14];
    const float* scorer_W       = (const float*)d_in[15];
    const float* scorer_b       = (const float*)d_in[16];
    const float* reuse_W        = (const float*)d_in[17];
    const float* reuse_b        = (const float*)d_in[18];

    float* out = (float*)d_out;
    float* out_probs = out;                 // (B, L)
    float* out_reuse = out + BB * LL;       // (B, L)

    char* ws = (char*)d_ws;
    float* h_new  = (float*)(ws);                          // 64 KB
    float* hp     = (float*)(ws + 65536);                  // 4 MB
    float* sv     = (float*)(ws + 65536 + 4194304);        // 32 KB
    float* rv     = (float*)(ws + 65536 + 4194304 + 32768);// 32 KB
    // xh_t (112 KB, used embed->gates) and logits (256 KB, used attn->finalsm)
    // have disjoint lifetimes -> share the same region.
    float* xh_t   = (float*)(ws + 65536 + 4194304 + 65536);
    float* logits = (float*)(ws + 65536 + 4194304 + 65536);

    hipLaunchKernelGGL(embed_kernel, dim3(112), dim3(256), 0, stream,
                       obj_id, obj_size, h0, obj_id_table, obj_size_table, xh_t);
    hipLaunchKernelGGL(gates_kernel, dim3(BB), dim3(256), 0, stream,
                       xh_t, W_ih, W_hh, b_ih, b_hh, c0, h_new);
    hipLaunchKernelGGL(proj_kernel, dim3(BB * 4), dim3(256), 0, stream,
                       history, h_new, attn_W, pos_table, scorer_W, reuse_W,
                       hp, sv, rv);
    hipLaunchKernelGGL(attn_kernel, dim3(BB * 16), dim3(256), 0, stream,
                       cache_lines, obj_id_table, hp, sv, rv,
                       scorer_b, reuse_b, logits, out_reuse);
    hipLaunchKernelGGL(finalsm_kernel, dim3(BB), dim3(256), 0, stream,
                       logits, lengths, out_probs);
}

// Round 3
// 202.550 us; speedup vs baseline: 1.2577x; 1.1167x over previous
//
#include <hip/hip_runtime.h>
#include <math.h>

#define BB 64
#define LL 1024
#define HH 256
#define TT 128
#define D_ID 128
#define D_SZ 64
#define D_POS 128
#define DX 192   // D_ID + D_SZ

typedef short s16x8 __attribute__((ext_vector_type(8)));
typedef float f32x16 __attribute__((ext_vector_type(16)));
typedef unsigned short u16x8 __attribute__((ext_vector_type(8)));

__device__ __forceinline__ unsigned short f2bf(float f) {
    unsigned u = __float_as_uint(f);
    unsigned r = u + 0x7fffu + ((u >> 16) & 1u);   // RNE
    return (unsigned short)(r >> 16);
}

// ------------------------------------------- xh_t[448][64] = concat(x, h0)^T
__global__ void embed_kernel(const int* __restrict__ obj_id,
                             const int* __restrict__ obj_size,
                             const float* __restrict__ h0,
                             const float* __restrict__ obj_id_table,
                             const float* __restrict__ obj_size_table,
                             float* __restrict__ xh_t) {
    int tid = threadIdx.x;
    int b = tid & 63;
    int k = blockIdx.x * 4 + (tid >> 6);
    float v;
    if (k < D_ID)      v = obj_id_table[(size_t)obj_id[b] * D_ID + k];
    else if (k < DX)   v = obj_size_table[(size_t)obj_size[b] * D_SZ + (k - D_ID)];
    else               v = h0[b * HH + (k - DX)];
    xh_t[k * 64 + b] = v;
}

// --------------- gates = xh @ [W_ih|W_hh]^T + b, fused LSTM activation
__global__ void gates_kernel(const float* __restrict__ xh_t,
                             const float* __restrict__ W_ih,
                             const float* __restrict__ W_hh,
                             const float* __restrict__ b_ih,
                             const float* __restrict__ b_hh,
                             const float* __restrict__ c0,
                             float* __restrict__ h_new) {
    int bid = blockIdx.x;
    int tid = threadIdx.x;
    int b = tid & 63;
    int joff = __builtin_amdgcn_readfirstlane(tid >> 6);
    int j = bid * 4 + joff;
    __shared__ float xhS[64 * 64];

    float acc[4];
#pragma unroll
    for (int q = 0; q < 4; ++q) acc[q] = b_ih[q * HH + j] + b_hh[q * HH + j];

    for (int kc = 0; kc < 7; ++kc) {
#pragma unroll
        for (int i = 0; i < 4; ++i)
            ((float4*)xhS)[i * 256 + tid] =
                ((const float4*)(xh_t + kc * 4096))[i * 256 + tid];
        __syncthreads();

        const float* w[4];
#pragma unroll
        for (int q = 0; q < 4; ++q) {
            int r = q * HH + j;
            w[q] = (kc < 3) ? (W_ih + (size_t)r * DX + kc * 64)
                            : (W_hh + (size_t)r * HH + (kc - 3) * 64);
        }
#pragma unroll 16
        for (int k = 0; k < 64; ++k) {
            float xv = xhS[k * 64 + b];
            acc[0] += w[0][k] * xv;
            acc[1] += w[1][k] * xv;
            acc[2] += w[2][k] * xv;
            acc[3] += w[3][k] * xv;
        }
        __syncthreads();
    }

    float ig = 1.f / (1.f + expf(-acc[0]));
    float fg = 1.f / (1.f + expf(-acc[1]));
    float gg = tanhf(acc[2]);
    float og = 1.f / (1.f + expf(-acc[3]));
    float c = fg * c0[b * HH + j] + ig * gg;
    h_new[b * HH + j] = og * tanhf(c);
}

// ------------- HP(bf16) = hist @ attn_W^T, sv, rv. grid: B*4, block 256
__global__ void proj_kernel(const float* __restrict__ history,
                            const float* __restrict__ h_new,
                            const float* __restrict__ attn_W,
                            const float* __restrict__ pos_table,
                            const float* __restrict__ scorer_W,
                            const float* __restrict__ reuse_W,
                            unsigned short* __restrict__ hp,
                            float* __restrict__ sv,
                            float* __restrict__ rv) {
    int b  = blockIdx.x >> 2;
    int t0 = (blockIdx.x & 3) * 32;
    int tid = threadIdx.x;
    int tx = tid & 15;
    int ty = tid >> 4;
    __shared__ float histS[32 * 68];
    __shared__ float wS[128 * 68];
    float acc[2][8];
#pragma unroll
    for (int j = 0; j < 2; ++j)
#pragma unroll
        for (int i = 0; i < 8; ++i) acc[j][i] = 0.f;
    float sva = 0.f, rva = 0.f;

    for (int kc = 0; kc < 4; ++kc) {
        int h0c = kc * 64;
#pragma unroll
        for (int i = 0; i < 2; ++i) {
            int idx = i * 256 + tid;
            int t = idx >> 4;
            int hq = (idx & 15) * 4;
            int gt = t0 + t;
            const float* src = (gt < TT - 1)
                ? (history + ((size_t)b * (TT - 1) + gt) * HH + h0c + hq)
                : (h_new + (size_t)b * HH + h0c + hq);
            *(float4*)(histS + t * 68 + hq) = *(const float4*)src;
        }
#pragma unroll
        for (int i = 0; i < 8; ++i) {
            int idx = i * 256 + tid;
            int d = idx >> 4;
            int hq = (idx & 15) * 4;
            *(float4*)(wS + d * 68 + hq) =
                *(const float4*)(attn_W + (size_t)d * HH + h0c + hq);
        }
        __syncthreads();

        for (int h = 0; h < 64; h += 4) {
            float4 hv[2];
#pragma unroll
            for (int j = 0; j < 2; ++j)
                hv[j] = *(const float4*)(histS + (ty + 16 * j) * 68 + h);
#pragma unroll
            for (int i = 0; i < 8; ++i) {
                float4 wv = *(const float4*)(wS + (tx + 16 * i) * 68 + h);
#pragma unroll
                for (int j = 0; j < 2; ++j)
                    acc[j][i] += hv[j].x * wv.x + hv[j].y * wv.y +
                                 hv[j].z * wv.z + hv[j].w * wv.w;
            }
        }
        if (tid < 32) {
            float s = 0.f, r = 0.f;
            for (int h = 0; h < 64; ++h) {
                float hval = histS[tid * 68 + h];
                s += hval * scorer_W[h0c + h];
                r += hval * reuse_W[h0c + h];
            }
            sva += s; rva += r;
        }
        __syncthreads();
    }
#pragma unroll
    for (int j = 0; j < 2; ++j) {
        int t = t0 + ty + 16 * j;
#pragma unroll
        for (int i = 0; i < 8; ++i) {
            int d = tx + 16 * i;
            hp[((size_t)b * TT + t) * D_ID + d] = f2bf(acc[j][i]);
        }
    }
    if (tid < 32) {
        int t = t0 + tid;
        float s = sva, r = rva;
        for (int p = 0; p < D_POS; ++p) {
            float pv = pos_table[(size_t)t * D_POS + p];
            s += pv * scorer_W[HH + p];
            r += pv * reuse_W[HH + p];
        }
        sv[b * TT + t] = s;
        rv[b * TT + t] = r;
    }
}

// ---- scores = Q@HP^T via mfma_32x32x16_bf16, softmax over t, heads
// grid: B*8 (128-l tiles), block 256 (4 waves; wave w owns 32 l-rows)
// LDS holds Q and HP pre-swizzled into MFMA fragment order:
//   frag layout A: A[m=lane&31][k=(lane>>5)*8+j], B: B[n=lane&31][k=(lane>>5)*8+j]
//   C layout   : col(t)=lane&31, row(l)=(reg&3)+8*(reg>>2)+4*(lane>>5)
__global__ void attn_kernel(const int* __restrict__ cache_lines,
                            const float* __restrict__ obj_id_table,
                            const unsigned short* __restrict__ hp,
                            const float* __restrict__ sv,
                            const float* __restrict__ rv,
                            const float* __restrict__ scorer_b,
                            const float* __restrict__ reuse_b,
                            float* __restrict__ logits,
                            float* __restrict__ out_reuse) {
    int b  = blockIdx.x >> 3;
    int l0 = (blockIdx.x & 7) * 128;
    int tid = threadIdx.x;
    __shared__ unsigned short qS[16384];   // [w][k][lane][8] : 4*8*64*8
    __shared__ unsigned short hpS[16384];  // [k][tt][lane][8]: 8*4*64*8

    // ---- stage Q: gather f32 rows, convert bf16, write fragment-order
    {
        int l = tid & 127;                 // row within l-tile
        int cl = cache_lines[b * LL + l0 + l];
        const float* qrow = obj_id_table + (size_t)cl * D_ID;
        int lhi = (l >> 5) * 8, llo = l & 31;
#pragma unroll
        for (int i = 0; i < 8; ++i) {
            int u = 2 * i + (tid >> 7);    // 8-float chunk index 0..15
            float4 f0 = *(const float4*)(qrow + u * 8);
            float4 f1 = *(const float4*)(qrow + u * 8 + 4);
            u16x8 p;
            p[0] = f2bf(f0.x); p[1] = f2bf(f0.y); p[2] = f2bf(f0.z); p[3] = f2bf(f0.w);
            p[4] = f2bf(f1.x); p[5] = f2bf(f1.y); p[6] = f2bf(f1.z); p[7] = f2bf(f1.w);
            *(u16x8*)(qS + (((lhi + (u >> 1)) * 64) + (u & 1) * 32 + llo) * 8) = p;
        }
    }
    // ---- stage HP (already bf16), fragment-order
    {
        int t = tid & 127;
        const unsigned short* hrow = hp + ((size_t)b * TT + t) * D_ID;
        int thi = t >> 5, tlo = t & 31;
#pragma unroll
        for (int i = 0; i < 8; ++i) {
            int u = 2 * i + (tid >> 7);
            u16x8 p = *(const u16x8*)(hrow + u * 8);
            *(u16x8*)(hpS + ((((u >> 1) * 4 + thi) * 64) + (u & 1) * 32 + tlo) * 8) = p;
        }
    }
    __syncthreads();

    int w = tid >> 6;
    int lane = tid & 63;
    int ln = lane & 31, half = lane >> 5;

    f32x16 acc[4];
#pragma unroll
    for (int tt = 0; tt < 4; ++tt)
#pragma unroll
        for (int r = 0; r < 16; ++r) acc[tt][r] = 0.f;

    const unsigned short* qw = qS + w * 8 * 512;
#pragma unroll
    for (int k = 0; k < 8; ++k) {
        s16x8 a = *(const s16x8*)(qw + k * 512 + lane * 8);
#pragma unroll
        for (int tt = 0; tt < 4; ++tt) {
            s16x8 bf = *(const s16x8*)(hpS + (k * 4 + tt) * 512 + lane * 8);
            acc[tt] = __builtin_amdgcn_mfma_f32_32x32x16_bf16(a, bf, acc[tt], 0, 0, 0);
        }
    }

    // ---- fused softmax over t (128 cols = 4 tiles x 32 lanes) + heads
    float sv_r[4], rv_r[4];
#pragma unroll
    for (int tt = 0; tt < 4; ++tt) {
        sv_r[tt] = sv[b * TT + tt * 32 + ln];
        rv_r[tt] = rv[b * TT + tt * 32 + ln];
    }
    float sb = scorer_b[0], rb = reuse_b[0];

#pragma unroll
    for (int r = 0; r < 16; ++r) {
        float v0 = acc[0][r], v1 = acc[1][r], v2 = acc[2][r], v3 = acc[3][r];
        float m = fmaxf(fmaxf(v0, v1), fmaxf(v2, v3));
#pragma unroll
        for (int off = 1; off < 32; off <<= 1) m = fmaxf(m, __shfl_xor(m, off));
        float e0 = __expf(v0 - m), e1 = __expf(v1 - m),
              e2 = __expf(v2 - m), e3 = __expf(v3 - m);
        float s  = e0 + e1 + e2 + e3;
        float lg = e0 * sv_r[0] + e1 * sv_r[1] + e2 * sv_r[2] + e3 * sv_r[3];
        float rg = e0 * rv_r[0] + e1 * rv_r[1] + e2 * rv_r[2] + e3 * rv_r[3];
#pragma unroll
        for (int off = 1; off < 32; off <<= 1) {
            s  += __shfl_xor(s, off);
            lg += __shfl_xor(lg, off);
            rg += __shfl_xor(rg, off);
        }
        if (ln == 0) {
            int row = (r & 3) + 8 * (r >> 2) + 4 * half;
            int l = l0 + w * 32 + row;
            logits[b * LL + l] = lg / s + sb;
            out_reuse[b * LL + l] = rg / s + rb;
        }
    }
}

// -------------------------------------- masked softmax over L per batch
__global__ void finalsm_kernel(const float* __restrict__ logits,
                               const int* __restrict__ lengths,
                               float* __restrict__ out_probs) {
    int b = blockIdx.x;
    int tid = threadIdx.x;
    int valid = max(lengths[b], 1);
    float v[4];
    float m = -1e30f;
#pragma unroll
    for (int i = 0; i < 4; ++i) {
        int l = tid + 256 * i;
        v[i] = (l < valid) ? logits[b * LL + l] : -1e30f;
        m = fmaxf(m, v[i]);
    }
#pragma unroll
    for (int off = 1; off < 64; off <<= 1) m = fmaxf(m, __shfl_xor(m, off));
    __shared__ float redm[4];
    __shared__ float reds[4];
    int wave = tid >> 6;
    if ((tid & 63) == 0) redm[wave] = m;
    __syncthreads();
    m = fmaxf(fmaxf(redm[0], redm[1]), fmaxf(redm[2], redm[3]));
    float e[4];
    float s = 0.f;
#pragma unroll
    for (int i = 0; i < 4; ++i) {
        int l = tid + 256 * i;
        e[i] = (l < valid) ? expf(v[i] - m) : 0.f;
        s += e[i];
    }
#pragma unroll
    for (int off = 1; off < 64; off <<= 1) s += __shfl_xor(s, off);
    if ((tid & 63) == 0) reds[wave] = s;
    __syncthreads();
    s = reds[0] + reds[1] + reds[2] + reds[3];
    float inv = 1.f / s;
#pragma unroll
    for (int i = 0; i < 4; ++i)
        out_probs[b * LL + tid + 256 * i] = e[i] * inv;
}

extern "C" void kernel_launch(void* const* d_in, const int* in_sizes, int n_in,
                              void* d_out, int out_size, void* d_ws, size_t ws_size,
                              hipStream_t stream) {
    const int*   obj_id         = (const int*)d_in[0];
    const int*   obj_size       = (const int*)d_in[1];
    const int*   cache_lines    = (const int*)d_in[2];
    const int*   lengths        = (const int*)d_in[3];
    const float* c0             = (const float*)d_in[4];
    const float* h0             = (const float*)d_in[5];
    const float* history        = (const float*)d_in[6];
    const float* obj_id_table   = (const float*)d_in[7];
    const float* obj_size_table = (const float*)d_in[8];
    const float* pos_table      = (const float*)d_in[9];
    const float* W_ih           = (const float*)d_in[10];
    const float* W_hh           = (const float*)d_in[11];
    const float* b_ih           = (const float*)d_in[12];
    const float* b_hh           = (const float*)d_in[13];
    const float* attn_W         = (const float*)d_in[14];
    const float* scorer_W       = (const float*)d_in[15];
    const float* scorer_b       = (const float*)d_in[16];
    const float* reuse_W        = (const float*)d_in[17];
    const float* reuse_b        = (const float*)d_in[18];

    float* out = (float*)d_out;
    float* out_probs = out;                 // (B, L)
    float* out_reuse = out + BB * LL;       // (B, L)

    char* ws = (char*)d_ws;
    float*          h_new  = (float*)(ws);                    // 64 KB
    unsigned short* hp     = (unsigned short*)(ws + 65536);   // 2 MB bf16
    float*          sv     = (float*)(ws + 65536 + 2097152);
    float*          rv     = (float*)(ws + 65536 + 2097152 + 32768);
    float*          xh_t   = (float*)(ws + 65536 + 2097152 + 65536);
    float*          logits = (float*)(ws + 65536 + 2097152 + 65536);

    hipLaunchKernelGGL(embed_kernel, dim3(112), dim3(256), 0, stream,
                       obj_id, obj_size, h0, obj_id_table, obj_size_table, xh_t);
    hipLaunchKernelGGL(gates_kernel, dim3(BB), dim3(256), 0, stream,
                       xh_t, W_ih, W_hh, b_ih, b_hh, c0, h_new);
    hipLaunchKernelGGL(proj_kernel, dim3(BB * 4), dim3(256), 0, stream,
                       history, h_new, attn_W, pos_table, scorer_W, reuse_W,
                       hp, sv, rv);
    hipLaunchKernelGGL(attn_kernel, dim3(BB * 8), dim3(256), 0, stream,
                       cache_lines, obj_id_table, hp, sv, rv,
                       scorer_b, reuse_b, logits, out_reuse);
    hipLaunchKernelGGL(finalsm_kernel, dim3(BB), dim3(256), 0, stream,
                       logits, lengths, out_probs);
}

// Round 4
// 165.798 us; speedup vs baseline: 1.5364x; 1.2217x over previous
//
#include <hip/hip_runtime.h>
#include <math.h>

#define BB 64
#define LL 1024
#define HH 256
#define TT 128
#define D_ID 128
#define D_SZ 64
#define D_POS 128
#define DX 192   // D_ID + D_SZ

typedef short s16x8 __attribute__((ext_vector_type(8)));
typedef float f32x16 __attribute__((ext_vector_type(16)));
typedef unsigned short u16x8 __attribute__((ext_vector_type(8)));

__device__ __forceinline__ unsigned short f2bf(float f) {
    unsigned u = __float_as_uint(f);
    unsigned r = u + 0x7fffu + ((u >> 16) & 1u);   // RNE
    return (unsigned short)(r >> 16);
}

__device__ __forceinline__ s16x8 pack8(float4 a, float4 b) {
    u16x8 p;
    p[0] = f2bf(a.x); p[1] = f2bf(a.y); p[2] = f2bf(a.z); p[3] = f2bf(a.w);
    p[4] = f2bf(b.x); p[5] = f2bf(b.y); p[6] = f2bf(b.z); p[7] = f2bf(b.w);
    return (s16x8)p;
}

// ------------------------------------------- xh_t[448][64] = concat(x, h0)^T
__global__ void embed_kernel(const int* __restrict__ obj_id,
                             const int* __restrict__ obj_size,
                             const float* __restrict__ h0,
                             const float* __restrict__ obj_id_table,
                             const float* __restrict__ obj_size_table,
                             float* __restrict__ xh_t) {
    int tid = threadIdx.x;
    int b = tid & 63;
    int k = blockIdx.x * 4 + (tid >> 6);
    float v;
    if (k < D_ID)      v = obj_id_table[(size_t)obj_id[b] * D_ID + k];
    else if (k < DX)   v = obj_size_table[(size_t)obj_size[b] * D_SZ + (k - D_ID)];
    else               v = h0[b * HH + (k - DX)];
    xh_t[k * 64 + b] = v;
}

// --------------- gates + fused LSTM activation
// grid 256 (one j per block), block 256: wave q (=tid>>6) owns W row q*HH+j
// (wave-uniform -> scalar loads); xh_t read k-major, coalesced across b lanes.
__global__ void gates_kernel(const float* __restrict__ xh_t,
                             const float* __restrict__ W_ih,
                             const float* __restrict__ W_hh,
                             const float* __restrict__ b_ih,
                             const float* __restrict__ b_hh,
                             const float* __restrict__ c0,
                             float* __restrict__ h_new) {
    int j = blockIdx.x;
    int tid = threadIdx.x;
    int b = tid & 63;
    int q = __builtin_amdgcn_readfirstlane(tid >> 6);
    int r = q * HH + j;
    __shared__ float gS[256];

    float acc = b_ih[r] + b_hh[r];
    const float* wi = W_ih + (size_t)r * DX;
    const float* wh = W_hh + (size_t)r * HH;
#pragma unroll 16
    for (int k = 0; k < DX; ++k)
        acc += wi[k] * xh_t[k * 64 + b];
#pragma unroll 16
    for (int k = 0; k < HH; ++k)
        acc += wh[k] * xh_t[(DX + k) * 64 + b];
    gS[q * 64 + b] = acc;
    __syncthreads();

    if (tid < 64) {
        float ig = 1.f / (1.f + expf(-gS[tid]));
        float fg = 1.f / (1.f + expf(-gS[64 + tid]));
        float gg = tanhf(gS[128 + tid]);
        float og = 1.f / (1.f + expf(-gS[192 + tid]));
        float c = fg * c0[tid * HH + j] + ig * gg;
        h_new[tid * HH + j] = og * tanhf(c);
    }
}

// ------------- HP(bf16) = hist @ attn_W^T via 32x32x16 MFMA
// grid: B*16 (b, t-tile, d-tile), block 64 (1 wave). No LDS, no barriers:
// A/B fragments ([row=lane&31][k=half*8+j], 8 contiguous k) load directly
// from global rows as 2x float4 + bf16 pack.
__global__ void proj_kernel(const float* __restrict__ history,
                            const float* __restrict__ h_new,
                            const float* __restrict__ attn_W,
                            unsigned short* __restrict__ hp) {
    int blk = blockIdx.x;
    int b  = blk >> 4;
    int t0 = ((blk >> 2) & 3) * 32;
    int d0 = (blk & 3) * 32;
    int lane = threadIdx.x;
    int ln = lane & 31, half = lane >> 5;

    int t = t0 + ln;
    const float* arow = (t < TT - 1)
        ? history + ((size_t)b * (TT - 1) + t) * HH
        : h_new + (size_t)b * HH;
    const float* brow = attn_W + (size_t)(d0 + ln) * HH;

    f32x16 acc;
#pragma unroll
    for (int r = 0; r < 16; ++r) acc[r] = 0.f;

#pragma unroll
    for (int ks = 0; ks < 16; ++ks) {
        int off = ks * 16 + half * 8;
        float4 a0 = *(const float4*)(arow + off);
        float4 a1 = *(const float4*)(arow + off + 4);
        float4 b0 = *(const float4*)(brow + off);
        float4 b1 = *(const float4*)(brow + off + 4);
        acc = __builtin_amdgcn_mfma_f32_32x32x16_bf16(
            pack8(a0, a1), pack8(b0, b1), acc, 0, 0, 0);
    }

#pragma unroll
    for (int r = 0; r < 16; ++r) {
        int tt = t0 + (r & 3) + 8 * (r >> 2) + 4 * half;
        hp[((size_t)b * TT + tt) * D_ID + d0 + ln] = f2bf(acc[r]);
    }
}

// ------------- sv/rv: [hist|pos] . scorer_W / reuse_W
// grid 128 (b*2 + which), block 128 (t)
__global__ void svrv_kernel(const float* __restrict__ history,
                            const float* __restrict__ h_new,
                            const float* __restrict__ pos_table,
                            const float* __restrict__ scorer_W,
                            const float* __restrict__ reuse_W,
                            float* __restrict__ sv,
                            float* __restrict__ rv) {
    int b = blockIdx.x >> 1;
    int which = blockIdx.x & 1;
    int t = threadIdx.x;
    const float* w = which ? reuse_W : scorer_W;
    const float* hrow = (t < TT - 1)
        ? history + ((size_t)b * (TT - 1) + t) * HH
        : h_new + (size_t)b * HH;
    float acc = 0.f;
#pragma unroll 8
    for (int k = 0; k < HH / 4; ++k) {
        float4 hv = *(const float4*)(hrow + 4 * k);
        float4 wv = *(const float4*)(w + 4 * k);
        acc += hv.x * wv.x + hv.y * wv.y + hv.z * wv.z + hv.w * wv.w;
    }
    const float* prow = pos_table + (size_t)t * D_POS;
#pragma unroll 8
    for (int k = 0; k < D_POS / 4; ++k) {
        float4 pv = *(const float4*)(prow + 4 * k);
        float4 wv = *(const float4*)(w + HH + 4 * k);
        acc += pv.x * wv.x + pv.y * wv.y + pv.z * wv.z + pv.w * wv.w;
    }
    (which ? rv : sv)[b * TT + t] = acc;
}

// ---- scores = Q@HP^T via mfma_32x32x16_bf16, softmax over t, heads
// grid: B*8 (128-l tiles), block 256 (4 waves; wave w owns 32 l-rows)
__global__ void attn_kernel(const int* __restrict__ cache_lines,
                            const float* __restrict__ obj_id_table,
                            const unsigned short* __restrict__ hp,
                            const float* __restrict__ sv,
                            const float* __restrict__ rv,
                            const float* __restrict__ scorer_b,
                            const float* __restrict__ reuse_b,
                            float* __restrict__ logits,
                            float* __restrict__ out_reuse) {
    int b  = blockIdx.x >> 3;
    int l0 = (blockIdx.x & 7) * 128;
    int tid = threadIdx.x;
    __shared__ unsigned short qS[16384];   // [w][k][lane][8]
    __shared__ unsigned short hpS[16384];  // [k][tt][lane][8]

    {
        int l = tid & 127;
        int cl = cache_lines[b * LL + l0 + l];
        const float* qrow = obj_id_table + (size_t)cl * D_ID;
        int lhi = (l >> 5) * 8, llo = l & 31;
#pragma unroll
        for (int i = 0; i < 8; ++i) {
            int u = 2 * i + (tid >> 7);
            float4 f0 = *(const float4*)(qrow + u * 8);
            float4 f1 = *(const float4*)(qrow + u * 8 + 4);
            *(s16x8*)(qS + (((lhi + (u >> 1)) * 64) + (u & 1) * 32 + llo) * 8) =
                pack8(f0, f1);
        }
    }
    {
        int t = tid & 127;
        const unsigned short* hrow = hp + ((size_t)b * TT + t) * D_ID;
        int thi = t >> 5, tlo = t & 31;
#pragma unroll
        for (int i = 0; i < 8; ++i) {
            int u = 2 * i + (tid >> 7);
            u16x8 p = *(const u16x8*)(hrow + u * 8);
            *(u16x8*)(hpS + ((((u >> 1) * 4 + thi) * 64) + (u & 1) * 32 + tlo) * 8) = p;
        }
    }
    __syncthreads();

    int w = tid >> 6;
    int lane = tid & 63;
    int ln = lane & 31, half = lane >> 5;

    f32x16 acc[4];
#pragma unroll
    for (int tt = 0; tt < 4; ++tt)
#pragma unroll
        for (int r = 0; r < 16; ++r) acc[tt][r] = 0.f;

    const unsigned short* qw = qS + w * 8 * 512;
#pragma unroll
    for (int k = 0; k < 8; ++k) {
        s16x8 a = *(const s16x8*)(qw + k * 512 + lane * 8);
#pragma unroll
        for (int tt = 0; tt < 4; ++tt) {
            s16x8 bf = *(const s16x8*)(hpS + (k * 4 + tt) * 512 + lane * 8);
            acc[tt] = __builtin_amdgcn_mfma_f32_32x32x16_bf16(a, bf, acc[tt], 0, 0, 0);
        }
    }

    float sv_r[4], rv_r[4];
#pragma unroll
    for (int tt = 0; tt < 4; ++tt) {
        sv_r[tt] = sv[b * TT + tt * 32 + ln];
        rv_r[tt] = rv[b * TT + tt * 32 + ln];
    }
    float sb = scorer_b[0], rb = reuse_b[0];

#pragma unroll
    for (int r = 0; r < 16; ++r) {
        float v0 = acc[0][r], v1 = acc[1][r], v2 = acc[2][r], v3 = acc[3][r];
        float m = fmaxf(fmaxf(v0, v1), fmaxf(v2, v3));
#pragma unroll
        for (int off = 1; off < 32; off <<= 1) m = fmaxf(m, __shfl_xor(m, off));
        float e0 = __expf(v0 - m), e1 = __expf(v1 - m),
              e2 = __expf(v2 - m), e3 = __expf(v3 - m);
        float s  = e0 + e1 + e2 + e3;
        float lg = e0 * sv_r[0] + e1 * sv_r[1] + e2 * sv_r[2] + e3 * sv_r[3];
        float rg = e0 * rv_r[0] + e1 * rv_r[1] + e2 * rv_r[2] + e3 * rv_r[3];
#pragma unroll
        for (int off = 1; off < 32; off <<= 1) {
            s  += __shfl_xor(s, off);
            lg += __shfl_xor(lg, off);
            rg += __shfl_xor(rg, off);
        }
        if (ln == 0) {
            int row = (r & 3) + 8 * (r >> 2) + 4 * half;
            int l = l0 + w * 32 + row;
            logits[b * LL + l] = lg / s + sb;
            out_reuse[b * LL + l] = rg / s + rb;
        }
    }
}

// -------------------------------------- masked softmax over L per batch
__global__ void finalsm_kernel(const float* __restrict__ logits,
                               const int* __restrict__ lengths,
                               float* __restrict__ out_probs) {
    int b = blockIdx.x;
    int tid = threadIdx.x;
    int valid = max(lengths[b], 1);
    float v[4];
    float m = -1e30f;
#pragma unroll
    for (int i = 0; i < 4; ++i) {
        int l = tid + 256 * i;
        v[i] = (l < valid) ? logits[b * LL + l] : -1e30f;
        m = fmaxf(m, v[i]);
    }
#pragma unroll
    for (int off = 1; off < 64; off <<= 1) m = fmaxf(m, __shfl_xor(m, off));
    __shared__ float redm[4];
    __shared__ float reds[4];
    int wave = tid >> 6;
    if ((tid & 63) == 0) redm[wave] = m;
    __syncthreads();
    m = fmaxf(fmaxf(redm[0], redm[1]), fmaxf(redm[2], redm[3]));
    float e[4];
    float s = 0.f;
#pragma unroll
    for (int i = 0; i < 4; ++i) {
        int l = tid + 256 * i;
        e[i] = (l < valid) ? expf(v[i] - m) : 0.f;
        s += e[i];
    }
#pragma unroll
    for (int off = 1; off < 64; off <<= 1) s += __shfl_xor(s, off);
    if ((tid & 63) == 0) reds[wave] = s;
    __syncthreads();
    s = reds[0] + reds[1] + reds[2] + reds[3];
    float inv = 1.f / s;
#pragma unroll
    for (int i = 0; i < 4; ++i)
        out_probs[b * LL + tid + 256 * i] = e[i] * inv;
}

extern "C" void kernel_launch(void* const* d_in, const int* in_sizes, int n_in,
                              void* d_out, int out_size, void* d_ws, size_t ws_size,
                              hipStream_t stream) {
    const int*   obj_id         = (const int*)d_in[0];
    const int*   obj_size       = (const int*)d_in[1];
    const int*   cache_lines    = (const int*)d_in[2];
    const int*   lengths        = (const int*)d_in[3];
    const float* c0             = (const float*)d_in[4];
    const float* h0             = (const float*)d_in[5];
    const float* history        = (const float*)d_in[6];
    const float* obj_id_table   = (const float*)d_in[7];
    const float* obj_size_table = (const float*)d_in[8];
    const float* pos_table      = (const float*)d_in[9];
    const float* W_ih           = (const float*)d_in[10];
    const float* W_hh           = (const float*)d_in[11];
    const float* b_ih           = (const float*)d_in[12];
    const float* b_hh           = (const float*)d_in[13];
    const float* attn_W         = (const float*)d_in[14];
    const float* scorer_W       = (const float*)d_in[15];
    const float* scorer_b       = (const float*)d_in[16];
    const float* reuse_W        = (const float*)d_in[17];
    const float* reuse_b        = (const float*)d_in[18];

    float* out = (float*)d_out;
    float* out_probs = out;                 // (B, L)
    float* out_reuse = out + BB * LL;       // (B, L)

    char* ws = (char*)d_ws;
    float*          h_new  = (float*)(ws);                    // 64 KB
    unsigned short* hp     = (unsigned short*)(ws + 65536);   // 2 MB bf16
    float*          sv     = (float*)(ws + 65536 + 2097152);
    float*          rv     = (float*)(ws + 65536 + 2097152 + 32768);
    float*          xh_t   = (float*)(ws + 65536 + 2097152 + 65536);
    float*          logits = (float*)(ws + 65536 + 2097152 + 65536);

    hipLaunchKernelGGL(embed_kernel, dim3(112), dim3(256), 0, stream,
                       obj_id, obj_size, h0, obj_id_table, obj_size_table, xh_t);
    hipLaunchKernelGGL(gates_kernel, dim3(HH), dim3(256), 0, stream,
                       xh_t, W_ih, W_hh, b_ih, b_hh, c0, h_new);
    hipLaunchKernelGGL(proj_kernel, dim3(BB * 16), dim3(64), 0, stream,
                       history, h_new, attn_W, hp);
    hipLaunchKernelGGL(svrv_kernel, dim3(BB * 2), dim3(TT), 0, stream,
                       history, h_new, pos_table, scorer_W, reuse_W, sv, rv);
    hipLaunchKernelGGL(attn_kernel, dim3(BB * 8), dim3(256), 0, stream,
                       cache_lines, obj_id_table, hp, sv, rv,
                       scorer_b, reuse_b, logits, out_reuse);
    hipLaunchKernelGGL(finalsm_kernel, dim3(BB), dim3(256), 0, stream,
                       logits, lengths, out_probs);
}